// Round 7
// baseline (171.408 us; speedup 1.0000x reference)
//
#include <hip/hip_runtime.h>

#define D 64
#define KP 50          // neighbors per row
#define NIT 10000      // R row stride
#define STR 68         // padded LDS row stride (tab kernels only)

#define RFL __builtin_amdgcn_readfirstlane

// ---------------- wave-level helpers (no LDS, no barriers) ----------------------

// Coalesced score phase for 2 rows: for each k, all lanes read row ix_k together.
// Result: lane k holds s_k. ia/w2 are per-lane (lane = d).
__device__ inline void score2(int ix0, int ix1, const float* __restrict__ XA,
                              float ia0, float ia1, float w2, int lane,
                              float& sc0, float& sc1) {
  sc0 = 0.f;
  sc1 = 0.f;
#pragma unroll 5
  for (int k = 0; k < KP; ++k) {
    const int a0 = RFL(__shfl(ix0, k, 64));
    const int a1 = RFL(__shfl(ix1, k, 64));
    float t0 = fmaxf(XA[(size_t)a0 * D + lane] + ia0, 0.f) * w2;
    float t1 = fmaxf(XA[(size_t)a1 * D + lane] + ia1, 0.f) * w2;
#pragma unroll
    for (int o = 1; o < 64; o <<= 1) {
      t0 += __shfl_xor(t0, o, 64);
      t1 += __shfl_xor(t1, o, 64);
    }
    sc0 = (lane == k) ? t0 : sc0;
    sc1 = (lane == k) ? t1 : sc1;
  }
}

// masked softmax over lanes 0..KP-1; lanes >= KP return 0
__device__ inline float softmax50(float val, int lane) {
  val = (lane < KP) ? val : -1e30f;
  float m = val;
#pragma unroll
  for (int o = 1; o < 64; o <<= 1) m = fmaxf(m, __shfl_xor(m, o, 64));
  float e = (lane < KP) ? __expf(val - m) : 0.f;
  float s = e;
#pragma unroll
  for (int o = 1; o < 64; o <<= 1) s += __shfl_xor(s, o, 64);
  return e / s;
}

// v[lane] = sum_k a_k * T[ix_k][lane], two rows at once (coalesced row reads)
__device__ inline void wsum2(float a0, float a1, int ix0, int ix1,
                             const float* __restrict__ T, int lane, float& v0,
                             float& v1) {
  v0 = 0.f;
  v1 = 0.f;
#pragma unroll 10
  for (int k = 0; k < KP; ++k) {
    const int i0 = RFL(__shfl(ix0, k, 64));
    const int i1 = RFL(__shfl(ix1, k, 64));
    const float c0 = __shfl(a0, k, 64);
    const float c1 = __shfl(a1, k, 64);
    v0 = fmaf(c0, T[(size_t)i0 * D + lane], v0);
    v1 = fmaf(c1, T[(size_t)i1 * D + lane], v1);
  }
}

// y[lane] = act(bias + sum_j v_j * W[j][lane]) for two rows, sharing W loads
template <bool RELU>
__device__ inline void mv64b2(float v0, float v1, const float* __restrict__ W,
                              const float* __restrict__ bias, int lane,
                              float& y0, float& y1) {
  float a0 = bias[lane], a1 = a0;
#pragma unroll 8
  for (int j = 0; j < D; ++j) {
    const float w = W[j * D + lane];
    a0 = fmaf(__shfl(v0, j, 64), w, a0);
    a1 = fmaf(__shfl(v1, j, 64), w, a1);
  }
  y0 = RELU ? fmaxf(a0, 0.f) : a0;
  y1 = RELU ? fmaxf(a1, 0.f) : a1;
}

// relu(bias + concat(lo,hi) @ W) for two rows, sharing W loads
__device__ inline void mv128b2(float lo0, float hi0, float lo1, float hi1,
                               const float* __restrict__ W,
                               const float* __restrict__ bias, int lane,
                               float& y0, float& y1) {
  float a0 = bias[lane], a1 = a0;
#pragma unroll 8
  for (int j = 0; j < D; ++j) {
    const float w = W[j * D + lane];
    a0 = fmaf(__shfl(lo0, j, 64), w, a0);
    a1 = fmaf(__shfl(lo1, j, 64), w, a1);
  }
#pragma unroll 8
  for (int j = 0; j < D; ++j) {
    const float w = W[(D + j) * D + lane];
    a0 = fmaf(__shfl(hi0, j, 64), w, a0);
    a1 = fmaf(__shfl(hi1, j, 64), w, a1);
  }
  y0 = fmaxf(a0, 0.f);
  y1 = fmaxf(a1, 0.f);
}

// ---------------- dense table kernels (LDS tile + SGPR-W matmul) ----------------

// acc[dd] += sum_j Xr[j] * Wp[j*D + dd]   (Wp wave-uniform -> s_load)
__device__ inline void mm16(const float* Xr, const float* __restrict__ Wp,
                            float acc[16]) {
  for (int j4 = 0; j4 < D; j4 += 4) {
    float4 xv = *(const float4*)&Xr[j4];
    const float xr[4] = {xv.x, xv.y, xv.z, xv.w};
#pragma unroll
    for (int jj = 0; jj < 4; ++jj) {
#pragma unroll
      for (int dd = 0; dd < 16; ++dd)
        acc[dd] = fmaf(xr[jj], Wp[(j4 + jj) * D + dd], acc[dd]);
    }
  }
}

// gate tables: X5[g][r] = relu(emb[g] @ Wg_lo + op_emb[r] @ Wg_hi + bg)
__global__ __launch_bounds__(256) void k_tab_gate(
    const float* __restrict__ item_emb, const float* __restrict__ user_emb,
    const float* __restrict__ op_emb, const float* __restrict__ ia_Wg,
    const float* __restrict__ ia_bg, const float* __restrict__ ua_Wg,
    const float* __restrict__ ua_bg, float* __restrict__ X5,
    float* __restrict__ F5, int nrows, int nb) {
  __shared__ float X[64 * STR];
  __shared__ float opbg[5][D];
  const bool second = (int)blockIdx.x >= nb;
  const float* emb = second ? user_emb : item_emb;
  const float* Wg = second ? ua_Wg : ia_Wg;
  const float* bg = second ? ua_bg : ia_bg;
  float* dst = second ? F5 : X5;
  const int blk = second ? blockIdx.x - nb : blockIdx.x;
  const int t = threadIdx.x, lane = t & 63, kw = t >> 6;
  const int g0 = blk * 64;
  for (int r = kw; r < 5; r += 4) {
    float acc = bg[lane];
    for (int j = 0; j < D; ++j)
      acc = fmaf(op_emb[r * D + j], Wg[(D + j) * D + lane], acc);
    opbg[r][lane] = acc;
  }
  for (int k = kw; k < 64; k += 4) {
    int g = g0 + k;
    if (g >= nrows) g = nrows - 1;
    X[k * STR + lane] = emb[(size_t)g * D + lane];
  }
  __syncthreads();
  const int dwu = RFL(kw << 4);
  float acc[16];
#pragma unroll
  for (int dd = 0; dd < 16; ++dd) acc[dd] = 0.f;
  mm16(&X[lane * STR], &Wg[dwu], acc);
  __syncthreads();
#pragma unroll
  for (int dd4 = 0; dd4 < 16; dd4 += 4)
    *(float4*)&X[lane * STR + dwu + dd4] =
        make_float4(acc[dd4], acc[dd4 + 1], acc[dd4 + 2], acc[dd4 + 3]);
  __syncthreads();
  for (int k = kw; k < 64; k += 4) {
    int g = g0 + k;
    if (g >= nrows) continue;
    float base = X[k * STR + lane];
#pragma unroll
    for (int r = 0; r < 5; ++r)
      dst[((size_t)g * 5 + r) * D + lane] = fmaxf(base + opbg[r][lane], 0.f);
  }
}

// five dense 64-wide GEMMs in one launch: dst = src @ W (+ bias)
struct Job {
  const float* src;
  const float* W;
  const float* bias;
  float* dst;
  int nrows;
};
struct Jobs5 {
  Job j[5];
  int off[5];
};

__global__ __launch_bounds__(256) void k_tab_mm5(Jobs5 J) {
  __shared__ float X[64 * STR];
  int bid = blockIdx.x;
  int s = 0;
  while (s < 4 && bid >= J.off[s + 1]) ++s;
  const Job jb = J.j[s];
  const int blk = bid - J.off[s];
  const int t = threadIdx.x, lane = t & 63, kw = t >> 6;
  const int g0 = blk * 64;
  for (int k = kw; k < 64; k += 4) {
    int g = g0 + k;
    if (g >= jb.nrows) g = jb.nrows - 1;
    X[k * STR + lane] = jb.src[(size_t)g * D + lane];
  }
  __syncthreads();
  const int dwu = RFL(kw << 4);
  float acc[16];
#pragma unroll
  for (int dd = 0; dd < 16; ++dd) acc[dd] = 0.f;
  mm16(&X[lane * STR], &jb.W[dwu], acc);
  __syncthreads();
#pragma unroll
  for (int dd4 = 0; dd4 < 16; dd4 += 4)
    *(float4*)&X[lane * STR + dwu + dd4] =
        make_float4(acc[dd4], acc[dd4 + 1], acc[dd4 + 2], acc[dd4 + 3]);
  __syncthreads();
  const float bv = jb.bias ? jb.bias[lane] : 0.f;
  for (int k = kw; k < 64; k += 4) {
    int g = g0 + k;
    if (g >= jb.nrows) continue;
    jb.dst[(size_t)g * D + lane] = X[k * STR + lane] + bv;
  }
}

// ---------------- h_I_all: one wave per TWO users, zero barriers ----------------
__global__ __launch_bounds__(256, 4) void k_hIall(
    const int* __restrict__ C, const int* __restrict__ Rm,
    const float* __restrict__ X5, const float* __restrict__ XA5,
    const float* __restrict__ IAu, const float* __restrict__ ia_Wa2,
    const float* __restrict__ ia_W, const float* __restrict__ ia_b,
    const float* __restrict__ sa_Wa1, float* __restrict__ hI,
    float* __restrict__ HA) {
  const int lane = threadIdx.x & 63;
  const int u0 = RFL(blockIdx.x * 8 + ((threadIdx.x >> 6) << 1));
  const int u1 = u0 + 1;
  const int kk = lane < KP ? lane : KP - 1;
  const int c0 = C[u0 * KP + kk];
  const int c1 = C[u1 * KP + kk];
  const int ix0 = c0 * 5 + Rm[(size_t)u0 * NIT + c0];
  const int ix1 = c1 * 5 + Rm[(size_t)u1 * NIT + c1];
  const float ia0 = IAu[(size_t)u0 * D + lane];
  const float ia1 = IAu[(size_t)u1 * D + lane];
  const float w2 = ia_Wa2[lane];
  float sc0, sc1;
  score2(ix0, ix1, XA5, ia0, ia1, w2, lane, sc0, sc1);
  float a0 = softmax50(sc0, lane);
  float a1 = softmax50(sc1, lane);
  float v0, v1;
  wsum2(a0, a1, ix0, ix1, X5, lane, v0, v1);
  float h0, h1;
  mv64b2<true>(v0, v1, ia_W, ia_b, lane, h0, h1);
  hI[(size_t)u0 * D + lane] = h0;
  hI[(size_t)u1 * D + lane] = h1;
  float ha0 = 0.f, ha1 = 0.f;
#pragma unroll 8
  for (int j = 0; j < D; ++j) {
    const float w = sa_Wa1[j * D + lane];
    ha0 = fmaf(__shfl(h0, j, 64), w, ha0);
    ha1 = fmaf(__shfl(h1, j, 64), w, ha1);
  }
  HA[(size_t)u0 * D + lane] = ha0;
  HA[(size_t)u1 * D + lane] = ha1;
}

// ---------------- batch: one wave per TWO rows, zero barriers -------------------
__global__ __launch_bounds__(256, 4) void k_batch(
    const int* __restrict__ user_idx, const int* __restrict__ item_idx,
    const int* __restrict__ Nn, const int* __restrict__ Bm,
    const int* __restrict__ Rm, const float* __restrict__ hIa,
    const float* __restrict__ HA, const float* __restrict__ F5,
    const float* __restrict__ FA5, const float* __restrict__ SAu,
    const float* __restrict__ UAt, const float* __restrict__ sa_Wa2,
    const float* __restrict__ sa_W, const float* __restrict__ sa_b,
    const float* __restrict__ ua_Wa2, const float* __restrict__ ua_W,
    const float* __restrict__ ua_b, const float* __restrict__ fu_W1,
    const float* __restrict__ fu_b1, const float* __restrict__ fu_W2,
    const float* __restrict__ fu_b2, const float* __restrict__ fu_W3,
    const float* __restrict__ fu_b3, const float* __restrict__ rp_W1,
    const float* __restrict__ rp_b1, const float* __restrict__ rp_W2,
    const float* __restrict__ rp_b2, const float* __restrict__ rp_W3,
    const float* __restrict__ rp_b3, float* __restrict__ out) {
  const int lane = threadIdx.x & 63;
  const int b0 = RFL(blockIdx.x * 8 + ((threadIdx.x >> 6) << 1));
  const int b1 = b0 + 1;
  const int u0 = RFL(user_idx[b0]), u1 = RFL(user_idx[b1]);
  const int it0 = RFL(item_idx[b0]), it1 = RFL(item_idx[b1]);
  const int kk = lane < KP ? lane : KP - 1;
  const int nix0 = Nn[u0 * KP + kk], nix1 = Nn[u1 * KP + kk];
  const int bn0 = Bm[it0 * KP + kk], bn1 = Bm[it1 * KP + kk];
  const int ix20 = bn0 * 5 + Rm[(size_t)bn0 * NIT + it0];
  const int ix21 = bn1 * 5 + Rm[(size_t)bn1 * NIT + it1];
  const float hIu0 = hIa[(size_t)u0 * D + lane];
  const float hIu1 = hIa[(size_t)u1 * D + lane];
  // ---- phase S ----
  const float sa0 = SAu[(size_t)u0 * D + lane];
  const float sa1 = SAu[(size_t)u1 * D + lane];
  const float sw2 = sa_Wa2[lane];
  float sc0, sc1;
  score2(nix0, nix1, HA, sa0, sa1, sw2, lane, sc0, sc1);
  float a0 = softmax50(sc0, lane);
  float a1 = softmax50(sc1, lane);
  float v0, v1;
  wsum2(a0, a1, nix0, nix1, hIa, lane, v0, v1);
  float hS0, hS1;
  mv64b2<true>(v0, v1, sa_W, sa_b, lane, hS0, hS1);
  // ---- phase Z ----
  const float ua0 = UAt[(size_t)it0 * D + lane];
  const float ua1 = UAt[(size_t)it1 * D + lane];
  const float uw2 = ua_Wa2[lane];
  score2(ix20, ix21, FA5, ua0, ua1, uw2, lane, sc0, sc1);
  a0 = softmax50(sc0, lane);
  a1 = softmax50(sc1, lane);
  wsum2(a0, a1, ix20, ix21, F5, lane, v0, v1);
  float z0, z1;
  mv64b2<true>(v0, v1, ua_W, ua_b, lane, z0, z1);
  // ---- fu MLP on concat(hI[u], hS) ----
  float h0, h1;
  mv128b2(hIu0, hS0, hIu1, hS1, fu_W1, fu_b1, lane, h0, h1);
  mv64b2<true>(h0, h1, fu_W2, fu_b2, lane, h0, h1);
  mv64b2<true>(h0, h1, fu_W3, fu_b3, lane, h0, h1);
  // ---- rp MLP on concat(h, z) ----
  float g0, g1;
  mv128b2(h0, z0, h1, z1, rp_W1, rp_b1, lane, g0, g1);
  mv64b2<true>(g0, g1, rp_W2, rp_b2, lane, g0, g1);
  const float w3 = rp_W3[lane];
  float p0 = g0 * w3, p1 = g1 * w3;
#pragma unroll
  for (int o = 1; o < 64; o <<= 1) {
    p0 += __shfl_xor(p0, o, 64);
    p1 += __shfl_xor(p1, o, 64);
  }
  if (lane == 0) {
    const float bb = rp_b3[0];
    out[b0] = p0 + bb;
    out[b1] = p1 + bb;
  }
}

extern "C" void kernel_launch(void* const* d_in, const int* in_sizes, int n_in,
                              void* d_out, int out_size, void* d_ws,
                              size_t ws_size, hipStream_t stream) {
  const int* user_idx = (const int*)d_in[0];
  const int* item_idx = (const int*)d_in[1];
  const int* C = (const int*)d_in[2];
  const int* Nn = (const int*)d_in[3];
  const int* Bm = (const int*)d_in[4];
  const int* Rm = (const int*)d_in[5];
  const float* user_emb = (const float*)d_in[6];
  const float* item_emb = (const float*)d_in[7];
  const float* opinion_emb = (const float*)d_in[8];
  const float* ia_Wg = (const float*)d_in[9];
  const float* ia_bg = (const float*)d_in[10];
  const float* ua_Wg = (const float*)d_in[11];
  const float* ua_bg = (const float*)d_in[12];
  const float* ia_Wa1 = (const float*)d_in[13];
  const float* ia_ba1 = (const float*)d_in[14];
  const float* ia_Wa2 = (const float*)d_in[15];
  const float* ia_W = (const float*)d_in[17];
  const float* ia_b = (const float*)d_in[18];
  const float* sa_Wa1 = (const float*)d_in[19];
  const float* sa_ba1 = (const float*)d_in[20];
  const float* sa_Wa2 = (const float*)d_in[21];
  const float* sa_W = (const float*)d_in[23];
  const float* sa_b = (const float*)d_in[24];
  const float* ua_Wa1 = (const float*)d_in[25];
  const float* ua_ba1 = (const float*)d_in[26];
  const float* ua_Wa2 = (const float*)d_in[27];
  const float* ua_W = (const float*)d_in[29];
  const float* ua_b = (const float*)d_in[30];
  const float* fu_W1 = (const float*)d_in[31];
  const float* fu_b1 = (const float*)d_in[32];
  const float* fu_W2 = (const float*)d_in[33];
  const float* fu_b2 = (const float*)d_in[34];
  const float* rp_W1 = (const float*)d_in[35];
  const float* rp_b1 = (const float*)d_in[36];
  const float* rp_W2 = (const float*)d_in[37];
  const float* rp_b2 = (const float*)d_in[38];
  const float* fu_W3 = (const float*)d_in[39];
  const float* fu_b3 = (const float*)d_in[40];
  const float* rp_W3 = (const float*)d_in[41];
  const float* rp_b3 = (const float*)d_in[42];

  const int NU = in_sizes[6] / D;  // 10000 users
  const int B = in_sizes[0];       // 2048

  float* ws = (float*)d_ws;
  float* X5 = ws;                        // NU*5*D
  float* XA5 = X5 + (size_t)NU * 5 * D;  // NU*5*D
  float* F5 = XA5 + (size_t)NU * 5 * D;  // NU*5*D
  float* FA5 = F5 + (size_t)NU * 5 * D;  // NU*5*D
  float* hI = FA5 + (size_t)NU * 5 * D;  // NU*D
  float* HA = hI + (size_t)NU * D;       // NU*D
  float* IAu = HA + (size_t)NU * D;      // NU*D
  float* SAu = IAu + (size_t)NU * D;     // NU*D
  float* UAt = SAu + (size_t)NU * D;     // NU*D

  const int nb = (NU + 63) / 64;       // 157
  const int nb5 = (NU * 5 + 63) / 64;  // 782

  k_tab_gate<<<2 * nb, 256, 0, stream>>>(item_emb, user_emb, opinion_emb,
                                         ia_Wg, ia_bg, ua_Wg, ua_bg, X5, F5,
                                         NU, nb);
  Jobs5 J;
  J.j[0] = {X5, ia_Wa1, nullptr, XA5, NU * 5};
  J.j[1] = {F5, ua_Wa1, nullptr, FA5, NU * 5};
  J.j[2] = {user_emb, &ia_Wa1[D * D], ia_ba1, IAu, NU};
  J.j[3] = {user_emb, &sa_Wa1[D * D], sa_ba1, SAu, NU};
  J.j[4] = {item_emb, &ua_Wa1[D * D], ua_ba1, UAt, NU};
  J.off[0] = 0;
  J.off[1] = nb5;
  J.off[2] = 2 * nb5;
  J.off[3] = 2 * nb5 + nb;
  J.off[4] = 2 * nb5 + 2 * nb;
  const int total_mm = 2 * nb5 + 3 * nb;
  k_tab_mm5<<<total_mm, 256, 0, stream>>>(J);
  k_hIall<<<NU / 8, 256, 0, stream>>>(C, Rm, X5, XA5, IAu, ia_Wa2, ia_W, ia_b,
                                      sa_Wa1, hI, HA);
  k_batch<<<B / 8, 256, 0, stream>>>(user_idx, item_idx, Nn, Bm, Rm, hI, HA,
                                     F5, FA5, SAu, UAt, sa_Wa2, sa_W, sa_b,
                                     ua_Wa2, ua_W, ua_b, fu_W1, fu_b1, fu_W2,
                                     fu_b2, fu_W3, fu_b3, rp_W1, rp_b1, rp_W2,
                                     rp_b2, rp_W3, rp_b3, (float*)d_out);
}

// Round 8
// 149.030 us; speedup vs baseline: 1.1502x; 1.1502x over previous
//
#include <hip/hip_runtime.h>

#define D 64
#define KP 50          // neighbors per row
#define NIT 10000      // R row stride
#define STR 68         // padded LDS row stride (tab kernels only)

#define RFL __builtin_amdgcn_readfirstlane

// ---------------- wave-level helpers (no LDS, no barriers) ----------------------

// score = sum_d relu(xa[d] + ia[d]) * w2[d]; xa per-lane row, ia/w2 uniform (s_load)
__device__ inline float score_row(const float* xa, const float* __restrict__ ia,
                                  const float* __restrict__ w2) {
  float p = 0.f;
#pragma unroll 16
  for (int j = 0; j < D; ++j) p = fmaf(fmaxf(xa[j] + ia[j], 0.f), w2[j], p);
  return p;
}

// masked softmax over lanes 0..KP-1; lanes >= KP return 0
__device__ inline float softmax50(float val, int lane) {
  val = (lane < KP) ? val : -1e30f;
  float m = val;
#pragma unroll
  for (int o = 1; o < 64; o <<= 1) m = fmaxf(m, __shfl_xor(m, o, 64));
  float e = (lane < KP) ? __expf(val - m) : 0.f;
  float s = e;
#pragma unroll
  for (int o = 1; o < 64; o <<= 1) s += __shfl_xor(s, o, 64);
  return e / s;
}

// v[lane] = sum_k a_k * T[ix_k][lane]   (a, ix live in lane k; rows coalesced)
__device__ inline float wsum_rows(float a, int ix, const float* __restrict__ T,
                                  int lane) {
  float v = 0.f;
#pragma unroll 10
  for (int k = 0; k < KP; ++k) {
    int ixk = RFL(__shfl(ix, k, 64));
    float ak = __shfl(a, k, 64);
    v = fmaf(ak, T[(size_t)ixk * D + lane], v);
  }
  return v;
}

// y[lane] = act(bias[lane] + sum_j vin_j * W[j][lane]); vin broadcast via readlane
template <bool RELU>
__device__ inline float mv64b(float vin, const float* __restrict__ W,
                              const float* __restrict__ bias, int lane) {
  float acc = bias[lane];
#pragma unroll 8
  for (int j = 0; j < D; ++j)
    acc = fmaf(__shfl(vin, j, 64), W[j * D + lane], acc);
  return RELU ? fmaxf(acc, 0.f) : acc;
}

// y[lane] = relu(bias[lane] + sum_j cat(lo,hi)_j * W[j][lane]), J = 128
__device__ inline float mv128b(float lo, float hi, const float* __restrict__ W,
                               const float* __restrict__ bias, int lane) {
  float acc = bias[lane];
#pragma unroll 8
  for (int j = 0; j < D; ++j)
    acc = fmaf(__shfl(lo, j, 64), W[j * D + lane], acc);
#pragma unroll 8
  for (int j = 0; j < D; ++j)
    acc = fmaf(__shfl(hi, j, 64), W[(D + j) * D + lane], acc);
  return fmaxf(acc, 0.f);
}

// acc[dd] += sum_j Xr[j] * Wp[j*D + dd]   (Wp wave-uniform -> s_load)
__device__ inline void mm16(const float* Xr, const float* __restrict__ Wp,
                            float acc[16]) {
  for (int j4 = 0; j4 < D; j4 += 4) {
    float4 xv = *(const float4*)&Xr[j4];
    const float xr[4] = {xv.x, xv.y, xv.z, xv.w};
#pragma unroll
    for (int jj = 0; jj < 4; ++jj) {
#pragma unroll
      for (int dd = 0; dd < 16; ++dd)
        acc[dd] = fmaf(xr[jj], Wp[(j4 + jj) * D + dd], acc[dd]);
    }
  }
}

// ---------------- fused table kernel ------------------------------------------
// jobs (block-uniform s = blockIdx.x / nb):
//   s=0: item gate -> X5, XA5      s=1: user gate -> F5, FA5
//   s=2: IAu = user_emb @ ia_Wa1_hi + ia_ba1
//   s=3: SAu = user_emb @ sa_Wa1_hi + sa_ba1
//   s=4: UAt = item_emb @ ua_Wa1_hi + ua_ba1
__global__ __launch_bounds__(256, 4) void k_tabs(
    const float* __restrict__ item_emb, const float* __restrict__ user_emb,
    const float* __restrict__ op_emb, const float* __restrict__ ia_Wg,
    const float* __restrict__ ia_bg, const float* __restrict__ ua_Wg,
    const float* __restrict__ ua_bg, const float* __restrict__ ia_Wa1,
    const float* __restrict__ ia_ba1, const float* __restrict__ sa_Wa1,
    const float* __restrict__ sa_ba1, const float* __restrict__ ua_Wa1,
    const float* __restrict__ ua_ba1, float* __restrict__ X5,
    float* __restrict__ XA5, float* __restrict__ F5, float* __restrict__ FA5,
    float* __restrict__ IAu, float* __restrict__ SAu, float* __restrict__ UAt,
    int NU_, int nb) {
  __shared__ float xr[64 * STR];
  __shared__ float b2[64 * STR];
  __shared__ float opbg[5][D];
  const int t = threadIdx.x, lane = t & 63, kw = t >> 6;
  const int s = blockIdx.x / nb, blk = blockIdx.x % nb;
  const int g0 = blk * 64;
  const int dwu = RFL(kw << 4);

  if (s >= 2) {  // ---- light mv jobs ----
    const float* src = (s == 4) ? item_emb : user_emb;
    const float* W = (s == 2) ? &ia_Wa1[D * D]
                              : (s == 3) ? &sa_Wa1[D * D] : &ua_Wa1[D * D];
    const float* bias = (s == 2) ? ia_ba1 : (s == 3) ? sa_ba1 : ua_ba1;
    float* dst = (s == 2) ? IAu : (s == 3) ? SAu : UAt;
    for (int k = kw; k < 64; k += 4) {
      int g = g0 + k;
      if (g >= NU_) g = NU_ - 1;
      xr[k * STR + lane] = src[(size_t)g * D + lane];
    }
    __syncthreads();
    float acc[16];
#pragma unroll
    for (int dd = 0; dd < 16; ++dd) acc[dd] = 0.f;
    mm16(&xr[lane * STR], &W[dwu], acc);
    __syncthreads();
#pragma unroll
    for (int dd4 = 0; dd4 < 16; dd4 += 4)
      *(float4*)&xr[lane * STR + dwu + dd4] =
          make_float4(acc[dd4], acc[dd4 + 1], acc[dd4 + 2], acc[dd4 + 3]);
    __syncthreads();
    for (int k = kw; k < 64; k += 4) {
      int g = g0 + k;
      if (g >= NU_) continue;
      dst[(size_t)g * D + lane] = xr[k * STR + lane] + bias[lane];
    }
    return;
  }

  // ---- gate jobs ----
  const float* emb = s ? user_emb : item_emb;
  const float* Wg = s ? ua_Wg : ia_Wg;
  const float* bg = s ? ua_bg : ia_bg;
  const float* Wa = s ? ua_Wa1 : ia_Wa1;  // low 64 rows
  float* o5 = s ? F5 : X5;
  float* oA = s ? FA5 : XA5;
  for (int r = kw; r < 5; r += 4) {
    float acc = bg[lane];
    for (int j = 0; j < D; ++j)
      acc = fmaf(op_emb[r * D + j], Wg[(D + j) * D + lane], acc);
    opbg[r][lane] = acc;
  }
  for (int k = kw; k < 64; k += 4) {
    int g = g0 + k;
    if (g >= NU_) g = NU_ - 1;
    xr[k * STR + lane] = emb[(size_t)g * D + lane];
  }
  __syncthreads();
  float accB[16];
#pragma unroll
  for (int dd = 0; dd < 16; ++dd) accB[dd] = 0.f;
  mm16(&xr[lane * STR], &Wg[dwu], accB);  // base gate (pre-relu), in regs
  __syncthreads();                        // xr reads done, buffer reusable
  for (int r = 0; r < 5; ++r) {
#pragma unroll
    for (int dd4 = 0; dd4 < 16; dd4 += 4) {
      float4 o;
      o.x = fmaxf(accB[dd4 + 0] + opbg[r][dwu + dd4 + 0], 0.f);
      o.y = fmaxf(accB[dd4 + 1] + opbg[r][dwu + dd4 + 1], 0.f);
      o.z = fmaxf(accB[dd4 + 2] + opbg[r][dwu + dd4 + 2], 0.f);
      o.w = fmaxf(accB[dd4 + 3] + opbg[r][dwu + dd4 + 3], 0.f);
      *(float4*)&xr[lane * STR + dwu + dd4] = o;  // X5 row (lane = row)
    }
    __syncthreads();  // xr ready
    float accA[16];
#pragma unroll
    for (int dd = 0; dd < 16; ++dd) accA[dd] = 0.f;
    mm16(&xr[lane * STR], &Wa[dwu], accA);
    for (int k = kw; k < 64; k += 4) {  // coalesced X5 store
      int g = g0 + k;
      if (g < NU_) o5[((size_t)g * 5 + r) * D + lane] = xr[k * STR + lane];
    }
    __syncthreads();  // all xr reads (mm + store) done
#pragma unroll
    for (int dd4 = 0; dd4 < 16; dd4 += 4)
      *(float4*)&b2[lane * STR + dwu + dd4] =
          make_float4(accA[dd4], accA[dd4 + 1], accA[dd4 + 2], accA[dd4 + 3]);
    __syncthreads();  // b2 ready
    for (int k = kw; k < 64; k += 4) {  // coalesced XA5 store
      int g = g0 + k;
      if (g < NU_) oA[((size_t)g * 5 + r) * D + lane] = b2[k * STR + lane];
    }
  }
}

// ---------------- h_I_all: grid-strided waves with next-user prefetch ----------
__global__ __launch_bounds__(256, 8) void k_hIall(
    const int* __restrict__ C, const int* __restrict__ Rm,
    const float* __restrict__ X5, const float* __restrict__ XA5,
    const float* __restrict__ IAu, const float* __restrict__ ia_Wa2,
    const float* __restrict__ ia_W, const float* __restrict__ ia_b,
    const float* __restrict__ sa_Wa1, float* __restrict__ hI,
    float* __restrict__ HA, int NU_) {
  const int lane = threadIdx.x & 63;
  const int NW = gridDim.x * 4;
  const int kk = lane < KP ? lane : KP - 1;
  int u = RFL(blockIdx.x * 4 + (threadIdx.x >> 6));
  if (u >= NU_) return;
  int c = C[u * KP + kk];
  int rv = Rm[(size_t)u * NIT + c];  // random HBM gather (prefetched next iters)
  while (true) {
    const int un = u + NW;
    const bool more = un < NU_;
    const int up = more ? un : u;
    // issue next user's gathers before this user's ~4000-cyc compute
    int cn = C[up * KP + kk];
    int rvn = Rm[(size_t)up * NIT + cn];
    // ---- compute current user ----
    const int ix = c * 5 + rv;
    float sc = score_row(XA5 + (size_t)ix * D, IAu + (size_t)u * D, ia_Wa2);
    float a = softmax50(sc, lane);
    float v = wsum_rows(a, ix, X5, lane);
    float h = mv64b<true>(v, ia_W, ia_b, lane);
    hI[(size_t)u * D + lane] = h;
    float ha = 0.f;
#pragma unroll 8
    for (int j = 0; j < D; ++j)
      ha = fmaf(__shfl(h, j, 64), sa_Wa1[j * D + lane], ha);
    HA[(size_t)u * D + lane] = ha;
    if (!more) break;
    u = un;
    c = cn;
    rv = rvn;
  }
}

// ---------------- batch: one wave per row, zero barriers ------------------------
__global__ __launch_bounds__(256, 8) void k_batch(
    const int* __restrict__ user_idx, const int* __restrict__ item_idx,
    const int* __restrict__ Nn, const int* __restrict__ Bm,
    const int* __restrict__ Rm, const float* __restrict__ hIa,
    const float* __restrict__ HA, const float* __restrict__ F5,
    const float* __restrict__ FA5, const float* __restrict__ SAu,
    const float* __restrict__ UAt, const float* __restrict__ sa_Wa2,
    const float* __restrict__ sa_W, const float* __restrict__ sa_b,
    const float* __restrict__ ua_Wa2, const float* __restrict__ ua_W,
    const float* __restrict__ ua_b, const float* __restrict__ fu_W1,
    const float* __restrict__ fu_b1, const float* __restrict__ fu_W2,
    const float* __restrict__ fu_b2, const float* __restrict__ fu_W3,
    const float* __restrict__ fu_b3, const float* __restrict__ rp_W1,
    const float* __restrict__ rp_b1, const float* __restrict__ rp_W2,
    const float* __restrict__ rp_b2, const float* __restrict__ rp_W3,
    const float* __restrict__ rp_b3, float* __restrict__ out) {
  const int lane = threadIdx.x & 63;
  const int b = RFL(blockIdx.x * 4 + (threadIdx.x >> 6));
  const int u = RFL(user_idx[b]);
  const int it = RFL(item_idx[b]);
  const int kk = lane < KP ? lane : KP - 1;
  const int nix = Nn[u * KP + kk];  // social neighbor ids
  const int bn = Bm[it * KP + kk];  // item-side user ids
  const int ix2 = bn * 5 + Rm[(size_t)bn * NIT + it];
  const float hIu = hIa[(size_t)u * D + lane];
  // ---- phase S: social aggregation over (HA, hI) rows ----
  float sc = score_row(HA + (size_t)nix * D, SAu + (size_t)u * D, sa_Wa2);
  float a = softmax50(sc, lane);
  float v = wsum_rows(a, nix, hIa, lane);
  float hS = mv64b<true>(v, sa_W, sa_b, lane);
  // ---- phase Z: item-side aggregation over (FA5, F5) rows ----
  float sc2 = score_row(FA5 + (size_t)ix2 * D, UAt + (size_t)it * D, ua_Wa2);
  float a2 = softmax50(sc2, lane);
  float v2 = wsum_rows(a2, ix2, F5, lane);
  float z = mv64b<true>(v2, ua_W, ua_b, lane);
  // ---- fu MLP on concat(hI[u], hS) ----
  float h = mv128b(hIu, hS, fu_W1, fu_b1, lane);
  h = mv64b<true>(h, fu_W2, fu_b2, lane);
  h = mv64b<true>(h, fu_W3, fu_b3, lane);
  // ---- rp MLP on concat(h, z) ----
  float g = mv128b(h, z, rp_W1, rp_b1, lane);
  g = mv64b<true>(g, rp_W2, rp_b2, lane);
  float p = g * rp_W3[lane];
#pragma unroll
  for (int o = 1; o < 64; o <<= 1) p += __shfl_xor(p, o, 64);
  if (lane == 0) out[b] = p + rp_b3[0];
}

extern "C" void kernel_launch(void* const* d_in, const int* in_sizes, int n_in,
                              void* d_out, int out_size, void* d_ws,
                              size_t ws_size, hipStream_t stream) {
  const int* user_idx = (const int*)d_in[0];
  const int* item_idx = (const int*)d_in[1];
  const int* C = (const int*)d_in[2];
  const int* Nn = (const int*)d_in[3];
  const int* Bm = (const int*)d_in[4];
  const int* Rm = (const int*)d_in[5];
  const float* user_emb = (const float*)d_in[6];
  const float* item_emb = (const float*)d_in[7];
  const float* opinion_emb = (const float*)d_in[8];
  const float* ia_Wg = (const float*)d_in[9];
  const float* ia_bg = (const float*)d_in[10];
  const float* ua_Wg = (const float*)d_in[11];
  const float* ua_bg = (const float*)d_in[12];
  const float* ia_Wa1 = (const float*)d_in[13];
  const float* ia_ba1 = (const float*)d_in[14];
  const float* ia_Wa2 = (const float*)d_in[15];
  const float* ia_W = (const float*)d_in[17];
  const float* ia_b = (const float*)d_in[18];
  const float* sa_Wa1 = (const float*)d_in[19];
  const float* sa_ba1 = (const float*)d_in[20];
  const float* sa_Wa2 = (const float*)d_in[21];
  const float* sa_W = (const float*)d_in[23];
  const float* sa_b = (const float*)d_in[24];
  const float* ua_Wa1 = (const float*)d_in[25];
  const float* ua_ba1 = (const float*)d_in[26];
  const float* ua_Wa2 = (const float*)d_in[27];
  const float* ua_W = (const float*)d_in[29];
  const float* ua_b = (const float*)d_in[30];
  const float* fu_W1 = (const float*)d_in[31];
  const float* fu_b1 = (const float*)d_in[32];
  const float* fu_W2 = (const float*)d_in[33];
  const float* fu_b2 = (const float*)d_in[34];
  const float* rp_W1 = (const float*)d_in[35];
  const float* rp_b1 = (const float*)d_in[36];
  const float* rp_W2 = (const float*)d_in[37];
  const float* rp_b2 = (const float*)d_in[38];
  const float* fu_W3 = (const float*)d_in[39];
  const float* fu_b3 = (const float*)d_in[40];
  const float* rp_W3 = (const float*)d_in[41];
  const float* rp_b3 = (const float*)d_in[42];

  const int NU = in_sizes[6] / D;  // 10000 users
  const int B = in_sizes[0];       // 2048

  float* ws = (float*)d_ws;
  float* X5 = ws;                        // NU*5*D
  float* XA5 = X5 + (size_t)NU * 5 * D;  // NU*5*D
  float* F5 = XA5 + (size_t)NU * 5 * D;  // NU*5*D
  float* FA5 = F5 + (size_t)NU * 5 * D;  // NU*5*D
  float* hI = FA5 + (size_t)NU * 5 * D;  // NU*D
  float* HA = hI + (size_t)NU * D;       // NU*D
  float* IAu = HA + (size_t)NU * D;      // NU*D
  float* SAu = IAu + (size_t)NU * D;     // NU*D
  float* UAt = SAu + (size_t)NU * D;     // NU*D

  const int nb = (NU + 63) / 64;  // 157

  k_tabs<<<5 * nb, 256, 0, stream>>>(
      item_emb, user_emb, opinion_emb, ia_Wg, ia_bg, ua_Wg, ua_bg, ia_Wa1,
      ia_ba1, sa_Wa1, sa_ba1, ua_Wa1, ua_ba1, X5, XA5, F5, FA5, IAu, SAu, UAt,
      NU, nb);
  k_hIall<<<1024, 256, 0, stream>>>(C, Rm, X5, XA5, IAu, ia_Wa2, ia_W, ia_b,
                                    sa_Wa1, hI, HA, NU);
  k_batch<<<B / 4, 256, 0, stream>>>(user_idx, item_idx, Nn, Bm, Rm, hI, HA,
                                     F5, FA5, SAu, UAt, sa_Wa2, sa_W, sa_b,
                                     ua_Wa2, ua_W, ua_b, fu_W1, fu_b1, fu_W2,
                                     fu_b2, fu_W3, fu_b3, rp_W1, rp_b1, rp_W2,
                                     rp_b2, rp_W3, rp_b3, (float*)d_out);
}

// Round 9
// 129.037 us; speedup vs baseline: 1.3284x; 1.1549x over previous
//
#include <hip/hip_runtime.h>
#include <hip/hip_fp16.h>

#define D 64
#define KP 50          // neighbors per row
#define NIT 10000      // R row stride
#define STR 68         // padded LDS row stride (tab kernels only)

#define RFL __builtin_amdgcn_readfirstlane

__device__ inline float rlanef(float v, int l) {
  return __int_as_float(__builtin_amdgcn_readlane(__float_as_int(v), l));
}

// ---------------- wave-level helpers (no LDS, no barriers) ----------------------

// score = sum_d relu(xa[d] + ia[d]) * w2[d]; xa = per-lane fp16 row (128B),
// ia/w2 uniform fp32 (s_load).
__device__ inline float score_row_h(const __half* __restrict__ xa,
                                    const float* __restrict__ ia,
                                    const float* __restrict__ w2) {
  float p = 0.f;
#pragma unroll
  for (int j = 0; j < D; j += 8) {
    float4 q = *(const float4*)&xa[j];  // 8 halves
    const __half2* h2 = (const __half2*)&q;
#pragma unroll
    for (int m = 0; m < 4; ++m) {
      float2 f = __half22float2(h2[m]);
      p = fmaf(fmaxf(f.x + ia[j + 2 * m + 0], 0.f), w2[j + 2 * m + 0], p);
      p = fmaf(fmaxf(f.y + ia[j + 2 * m + 1], 0.f), w2[j + 2 * m + 1], p);
    }
  }
  return p;
}

// masked softmax over lanes 0..KP-1; lanes >= KP return 0
__device__ inline float softmax50(float val, int lane) {
  val = (lane < KP) ? val : -1e30f;
  float m = val;
#pragma unroll
  for (int o = 1; o < 64; o <<= 1) m = fmaxf(m, __shfl_xor(m, o, 64));
  float e = (lane < KP) ? __expf(val - m) : 0.f;
  float s = e;
#pragma unroll
  for (int o = 1; o < 64; o <<= 1) s += __shfl_xor(s, o, 64);
  return e / s;
}

// v[lane] = sum_k a_k * T[ix_k][64+lane]  (fp16 table, readlane broadcasts)
__device__ inline float wsum_rows_h(float a, int ix,
                                    const __half* __restrict__ T, int lane) {
  float v = 0.f;
#pragma unroll 10
  for (int k = 0; k < KP; ++k) {
    const int ixk = __builtin_amdgcn_readlane(ix, k);
    const float ak = rlanef(a, k);
    v = fmaf(ak, (float)T[(size_t)ixk * 128 + 64 + lane], v);
  }
  return v;
}

// y[lane] = act(bias[lane] + sum_j vin_j * W[j][lane]); vin via readlane (SGPR)
template <bool RELU>
__device__ inline float mv64b(float vin, const float* __restrict__ W,
                              const float* __restrict__ bias, int lane) {
  float acc = bias[lane];
#pragma unroll 8
  for (int j = 0; j < D; ++j)
    acc = fmaf(rlanef(vin, j), W[j * D + lane], acc);
  return RELU ? fmaxf(acc, 0.f) : acc;
}

// y[lane] = relu(bias[lane] + concat(lo,hi) @ W), J = 128
__device__ inline float mv128b(float lo, float hi, const float* __restrict__ W,
                               const float* __restrict__ bias, int lane) {
  float acc = bias[lane];
#pragma unroll 8
  for (int j = 0; j < D; ++j)
    acc = fmaf(rlanef(lo, j), W[j * D + lane], acc);
#pragma unroll 8
  for (int j = 0; j < D; ++j)
    acc = fmaf(rlanef(hi, j), W[(D + j) * D + lane], acc);
  return fmaxf(acc, 0.f);
}

// acc[dd] += sum_j Xr[j] * Wp[j*D + dd]   (Wp wave-uniform -> s_load)
__device__ inline void mm16(const float* Xr, const float* __restrict__ Wp,
                            float acc[16]) {
  for (int j4 = 0; j4 < D; j4 += 4) {
    float4 xv = *(const float4*)&Xr[j4];
    const float xr[4] = {xv.x, xv.y, xv.z, xv.w};
#pragma unroll
    for (int jj = 0; jj < 4; ++jj) {
#pragma unroll
      for (int dd = 0; dd < 16; ++dd)
        acc[dd] = fmaf(xr[jj], Wp[(j4 + jj) * D + dd], acc[dd]);
    }
  }
}

// ---------------- gate tables: upper half of XXA5/FFA5 --------------------------
// dst[(g*5+r)*128 + 64 + d] = fp16(relu(emb[g] @ Wg_lo + op_emb[r] @ Wg_hi + bg))
__global__ __launch_bounds__(256) void k_tab_gate(
    const float* __restrict__ item_emb, const float* __restrict__ user_emb,
    const float* __restrict__ op_emb, const float* __restrict__ ia_Wg,
    const float* __restrict__ ia_bg, const float* __restrict__ ua_Wg,
    const float* __restrict__ ua_bg, __half* __restrict__ XXA5,
    __half* __restrict__ FFA5, int nrows, int nb) {
  __shared__ float X[64 * STR];
  __shared__ float opbg[5][D];
  const bool second = (int)blockIdx.x >= nb;
  const float* emb = second ? user_emb : item_emb;
  const float* Wg = second ? ua_Wg : ia_Wg;
  const float* bg = second ? ua_bg : ia_bg;
  __half* dst = second ? FFA5 : XXA5;
  const int blk = second ? blockIdx.x - nb : blockIdx.x;
  const int t = threadIdx.x, lane = t & 63, kw = t >> 6;
  const int g0 = blk * 64;
  for (int r = kw; r < 5; r += 4) {
    float acc = bg[lane];
    for (int j = 0; j < D; ++j)
      acc = fmaf(op_emb[r * D + j], Wg[(D + j) * D + lane], acc);
    opbg[r][lane] = acc;
  }
  for (int k = kw; k < 64; k += 4) {
    int g = g0 + k;
    if (g >= nrows) g = nrows - 1;
    X[k * STR + lane] = emb[(size_t)g * D + lane];
  }
  __syncthreads();
  const int dwu = RFL(kw << 4);
  float acc[16];
#pragma unroll
  for (int dd = 0; dd < 16; ++dd) acc[dd] = 0.f;
  mm16(&X[lane * STR], &Wg[dwu], acc);
  __syncthreads();
#pragma unroll
  for (int dd4 = 0; dd4 < 16; dd4 += 4)
    *(float4*)&X[lane * STR + dwu + dd4] =
        make_float4(acc[dd4], acc[dd4 + 1], acc[dd4 + 2], acc[dd4 + 3]);
  __syncthreads();
  for (int k = kw; k < 64; k += 4) {
    int g = g0 + k;
    if (g >= nrows) continue;
    float base = X[k * STR + lane];
#pragma unroll
    for (int r = 0; r < 5; ++r)
      dst[((size_t)g * 5 + r) * 128 + 64 + lane] =
          __float2half(fmaxf(base + opbg[r][lane], 0.f));
  }
}

// ---------------- five dense 64-wide GEMMs in one launch ------------------------
struct Job {
  const void* src;
  int sStr, sOff, sHalf;
  const float* W;
  const float* bias;
  void* dst;
  int dStr, dOff, dHalf;
  int nrows;
};
struct Jobs5 {
  Job j[5];
  int off[5];
};

__global__ __launch_bounds__(256) void k_tab_mm5(Jobs5 J) {
  __shared__ float X[64 * STR];
  int bid = blockIdx.x;
  int s = 0;
  while (s < 4 && bid >= J.off[s + 1]) ++s;
  const Job jb = J.j[s];
  const int blk = bid - J.off[s];
  const int t = threadIdx.x, lane = t & 63, kw = t >> 6;
  const int g0 = blk * 64;
  for (int k = kw; k < 64; k += 4) {
    int g = g0 + k;
    if (g >= jb.nrows) g = jb.nrows - 1;
    const size_t idx = (size_t)g * jb.sStr + jb.sOff + lane;
    X[k * STR + lane] = jb.sHalf ? (float)((const __half*)jb.src)[idx]
                                 : ((const float*)jb.src)[idx];
  }
  __syncthreads();
  const int dwu = RFL(kw << 4);
  float acc[16];
#pragma unroll
  for (int dd = 0; dd < 16; ++dd) acc[dd] = 0.f;
  mm16(&X[lane * STR], &jb.W[dwu], acc);
  __syncthreads();
#pragma unroll
  for (int dd4 = 0; dd4 < 16; dd4 += 4)
    *(float4*)&X[lane * STR + dwu + dd4] =
        make_float4(acc[dd4], acc[dd4 + 1], acc[dd4 + 2], acc[dd4 + 3]);
  __syncthreads();
  const float bv = jb.bias ? jb.bias[lane] : 0.f;
  for (int k = kw; k < 64; k += 4) {
    int g = g0 + k;
    if (g >= jb.nrows) continue;
    const float val = X[k * STR + lane] + bv;
    const size_t idx = (size_t)g * jb.dStr + jb.dOff + lane;
    if (jb.dHalf)
      ((__half*)jb.dst)[idx] = __float2half(val);
    else
      ((float*)jb.dst)[idx] = val;
  }
}

// ---------------- h_I_all: one wave per user, zero barriers ---------------------
__global__ __launch_bounds__(256, 8) void k_hIall(
    const int* __restrict__ C, const int* __restrict__ Rm,
    const __half* __restrict__ XXA5, const float* __restrict__ IAu,
    const float* __restrict__ ia_Wa2, const float* __restrict__ ia_W,
    const float* __restrict__ ia_b, const float* __restrict__ sa_Wa1,
    __half* __restrict__ HHA) {
  const int lane = threadIdx.x & 63;
  const int u = RFL(blockIdx.x * 4 + (threadIdx.x >> 6));
  const int kk = lane < KP ? lane : KP - 1;
  const int c = C[u * KP + kk];
  const int ix = c * 5 + Rm[(size_t)u * NIT + c];  // random HBM gather
  float sc = score_row_h(XXA5 + (size_t)ix * 128, IAu + (size_t)u * D, ia_Wa2);
  float a = softmax50(sc, lane);
  float v = wsum_rows_h(a, ix, XXA5, lane);
  float h = mv64b<true>(v, ia_W, ia_b, lane);
  float ha = 0.f;
#pragma unroll 8
  for (int j = 0; j < D; ++j)
    ha = fmaf(rlanef(h, j), sa_Wa1[j * D + lane], ha);
  HHA[(size_t)u * 128 + lane] = __float2half(ha);       // HA half (score)
  HHA[(size_t)u * 128 + 64 + lane] = __float2half(h);   // hI half (wsum/MLP)
}

// ---------------- batch: one wave per row, zero barriers ------------------------
__global__ __launch_bounds__(256, 8) void k_batch(
    const int* __restrict__ user_idx, const int* __restrict__ item_idx,
    const int* __restrict__ Nn, const int* __restrict__ Bm,
    const int* __restrict__ Rm, const __half* __restrict__ HHA,
    const __half* __restrict__ FFA5, const float* __restrict__ SAu,
    const float* __restrict__ UAt, const float* __restrict__ sa_Wa2,
    const float* __restrict__ sa_W, const float* __restrict__ sa_b,
    const float* __restrict__ ua_Wa2, const float* __restrict__ ua_W,
    const float* __restrict__ ua_b, const float* __restrict__ fu_W1,
    const float* __restrict__ fu_b1, const float* __restrict__ fu_W2,
    const float* __restrict__ fu_b2, const float* __restrict__ fu_W3,
    const float* __restrict__ fu_b3, const float* __restrict__ rp_W1,
    const float* __restrict__ rp_b1, const float* __restrict__ rp_W2,
    const float* __restrict__ rp_b2, const float* __restrict__ rp_W3,
    const float* __restrict__ rp_b3, float* __restrict__ out) {
  const int lane = threadIdx.x & 63;
  const int b = RFL(blockIdx.x * 4 + (threadIdx.x >> 6));
  const int u = RFL(user_idx[b]);
  const int it = RFL(item_idx[b]);
  const int kk = lane < KP ? lane : KP - 1;
  const int nix = Nn[u * KP + kk];  // social neighbor ids
  const int bn = Bm[it * KP + kk];  // item-side user ids
  const int ix2 = bn * 5 + Rm[(size_t)bn * NIT + it];
  const float hIu = (float)HHA[(size_t)u * 128 + 64 + lane];
  // ---- phase S: social aggregation over HHA rows ----
  float sc = score_row_h(HHA + (size_t)nix * 128, SAu + (size_t)u * D, sa_Wa2);
  float a = softmax50(sc, lane);
  float v = wsum_rows_h(a, nix, HHA, lane);
  float hS = mv64b<true>(v, sa_W, sa_b, lane);
  // ---- phase Z: item-side aggregation over FFA5 rows ----
  float sc2 =
      score_row_h(FFA5 + (size_t)ix2 * 128, UAt + (size_t)it * D, ua_Wa2);
  float a2 = softmax50(sc2, lane);
  float v2 = wsum_rows_h(a2, ix2, FFA5, lane);
  float z = mv64b<true>(v2, ua_W, ua_b, lane);
  // ---- fu MLP on concat(hI[u], hS) ----
  float h = mv128b(hIu, hS, fu_W1, fu_b1, lane);
  h = mv64b<true>(h, fu_W2, fu_b2, lane);
  h = mv64b<true>(h, fu_W3, fu_b3, lane);
  // ---- rp MLP on concat(h, z) ----
  float g = mv128b(h, z, rp_W1, rp_b1, lane);
  g = mv64b<true>(g, rp_W2, rp_b2, lane);
  float p = g * rp_W3[lane];
#pragma unroll
  for (int o = 1; o < 64; o <<= 1) p += __shfl_xor(p, o, 64);
  if (lane == 0) out[b] = p + rp_b3[0];
}

extern "C" void kernel_launch(void* const* d_in, const int* in_sizes, int n_in,
                              void* d_out, int out_size, void* d_ws,
                              size_t ws_size, hipStream_t stream) {
  const int* user_idx = (const int*)d_in[0];
  const int* item_idx = (const int*)d_in[1];
  const int* C = (const int*)d_in[2];
  const int* Nn = (const int*)d_in[3];
  const int* Bm = (const int*)d_in[4];
  const int* Rm = (const int*)d_in[5];
  const float* user_emb = (const float*)d_in[6];
  const float* item_emb = (const float*)d_in[7];
  const float* opinion_emb = (const float*)d_in[8];
  const float* ia_Wg = (const float*)d_in[9];
  const float* ia_bg = (const float*)d_in[10];
  const float* ua_Wg = (const float*)d_in[11];
  const float* ua_bg = (const float*)d_in[12];
  const float* ia_Wa1 = (const float*)d_in[13];
  const float* ia_ba1 = (const float*)d_in[14];
  const float* ia_Wa2 = (const float*)d_in[15];
  const float* ia_W = (const float*)d_in[17];
  const float* ia_b = (const float*)d_in[18];
  const float* sa_Wa1 = (const float*)d_in[19];
  const float* sa_ba1 = (const float*)d_in[20];
  const float* sa_Wa2 = (const float*)d_in[21];
  const float* sa_W = (const float*)d_in[23];
  const float* sa_b = (const float*)d_in[24];
  const float* ua_Wa1 = (const float*)d_in[25];
  const float* ua_ba1 = (const float*)d_in[26];
  const float* ua_Wa2 = (const float*)d_in[27];
  const float* ua_W = (const float*)d_in[29];
  const float* ua_b = (const float*)d_in[30];
  const float* fu_W1 = (const float*)d_in[31];
  const float* fu_b1 = (const float*)d_in[32];
  const float* fu_W2 = (const float*)d_in[33];
  const float* fu_b2 = (const float*)d_in[34];
  const float* rp_W1 = (const float*)d_in[35];
  const float* rp_b1 = (const float*)d_in[36];
  const float* rp_W2 = (const float*)d_in[37];
  const float* rp_b2 = (const float*)d_in[38];
  const float* fu_W3 = (const float*)d_in[39];
  const float* fu_b3 = (const float*)d_in[40];
  const float* rp_W3 = (const float*)d_in[41];
  const float* rp_b3 = (const float*)d_in[42];

  const int NU = in_sizes[6] / D;  // 10000 users
  const int B = in_sizes[0];       // 2048

  // ws layout (halves first, then fp32 tables; all 16B-aligned)
  __half* XXA5 = (__half*)d_ws;                    // NU*5*128 halves
  __half* FFA5 = XXA5 + (size_t)NU * 5 * 128;      // NU*5*128 halves
  __half* HHA = FFA5 + (size_t)NU * 5 * 128;       // NU*128 halves
  float* IAu = (float*)(HHA + (size_t)NU * 128);   // NU*D fp32
  float* SAu = IAu + (size_t)NU * D;               // NU*D
  float* UAt = SAu + (size_t)NU * D;               // NU*D

  const int nb = (NU + 63) / 64;       // 157
  const int nb5 = (NU * 5 + 63) / 64;  // 782

  k_tab_gate<<<2 * nb, 256, 0, stream>>>(item_emb, user_emb, opinion_emb,
                                         ia_Wg, ia_bg, ua_Wg, ua_bg, XXA5,
                                         FFA5, NU, nb);
  Jobs5 J;
  J.j[0] = {XXA5, 128, 64, 1, ia_Wa1, nullptr, XXA5, 128, 0, 1, NU * 5};
  J.j[1] = {FFA5, 128, 64, 1, ua_Wa1, nullptr, FFA5, 128, 0, 1, NU * 5};
  J.j[2] = {user_emb, D, 0, 0, &ia_Wa1[D * D], ia_ba1, IAu, D, 0, 0, NU};
  J.j[3] = {user_emb, D, 0, 0, &sa_Wa1[D * D], sa_ba1, SAu, D, 0, 0, NU};
  J.j[4] = {item_emb, D, 0, 0, &ua_Wa1[D * D], ua_ba1, UAt, D, 0, 0, NU};
  J.off[0] = 0;
  J.off[1] = nb5;
  J.off[2] = 2 * nb5;
  J.off[3] = 2 * nb5 + nb;
  J.off[4] = 2 * nb5 + 2 * nb;
  k_tab_mm5<<<2 * nb5 + 3 * nb, 256, 0, stream>>>(J);
  k_hIall<<<NU / 4, 256, 0, stream>>>(C, Rm, XXA5, IAu, ia_Wa2, ia_W, ia_b,
                                      sa_Wa1, HHA);
  k_batch<<<B / 4, 256, 0, stream>>>(user_idx, item_idx, Nn, Bm, Rm, HHA, FFA5,
                                     SAu, UAt, sa_Wa2, sa_W, sa_b, ua_Wa2,
                                     ua_W, ua_b, fu_W1, fu_b1, fu_W2, fu_b2,
                                     fu_W3, fu_b3, rp_W1, rp_b1, rp_W2, rp_b2,
                                     rp_W3, rp_b3, (float*)d_out);
}

// Round 10
// 88.673 us; speedup vs baseline: 1.9330x; 1.4552x over previous
//
#include <hip/hip_runtime.h>
#include <hip/hip_fp16.h>

#define D 64
#define KP 50          // neighbors per row
#define NIT 10000      // R row stride

#define RFL __builtin_amdgcn_readfirstlane

typedef _Float16 half8 __attribute__((ext_vector_type(8)));
typedef float floatx4 __attribute__((ext_vector_type(4)));

__device__ inline float rlanef(float v, int l) {
  return __int_as_float(__builtin_amdgcn_readlane(__float_as_int(v), l));
}

// ---------------- MFMA fragment loaders (16x16x32 f16) --------------------------
// A-frag: lane l holds A[m = l&15][k = kc*32 + 8*(l>>4) + j], j=0..7  (fp32 src)
__device__ inline half8 loadA_f32(const float* __restrict__ src, int kc,
                                  int lane) {
  const float* p = src + (size_t)(lane & 15) * D + kc * 32 + 8 * (lane >> 4);
  float4 lo = *(const float4*)p;
  float4 hi = *(const float4*)(p + 4);
  half8 a;
  a[0] = (_Float16)lo.x; a[1] = (_Float16)lo.y;
  a[2] = (_Float16)lo.z; a[3] = (_Float16)lo.w;
  a[4] = (_Float16)hi.x; a[5] = (_Float16)hi.y;
  a[6] = (_Float16)hi.z; a[7] = (_Float16)hi.w;
  return a;
}

// B-frag: lane l holds B[k = kc*32 + 8*(l>>4)+j][n = 16*t + (l&15)]  (fp32 W, ld=D)
__device__ inline half8 loadB_f32(const float* __restrict__ W, int kc, int t,
                                  int lane) {
  const float* p =
      W + (size_t)(kc * 32 + 8 * (lane >> 4)) * D + 16 * t + (lane & 15);
  half8 b;
#pragma unroll
  for (int j = 0; j < 8; ++j) b[j] = (_Float16)p[(size_t)j * D];
  return b;
}

// ---------------- wave-level helpers (no LDS, no barriers) ----------------------

// score = sum_d relu(xa[d] + ia[d]) * w2[d]; split accumulators
__device__ inline float score_row_h(const __half* __restrict__ xa,
                                    const float* __restrict__ ia,
                                    const float* __restrict__ w2) {
  float p0 = 0.f, p1 = 0.f;
#pragma unroll
  for (int j = 0; j < D; j += 8) {
    float4 q = *(const float4*)&xa[j];
    const __half2* h2 = (const __half2*)&q;
#pragma unroll
    for (int m = 0; m < 4; ++m) {
      float2 f = __half22float2(h2[m]);
      p0 = fmaf(fmaxf(f.x + ia[j + 2 * m + 0], 0.f), w2[j + 2 * m + 0], p0);
      p1 = fmaf(fmaxf(f.y + ia[j + 2 * m + 1], 0.f), w2[j + 2 * m + 1], p1);
    }
  }
  return p0 + p1;
}

__device__ inline float softmax50(float val, int lane) {
  val = (lane < KP) ? val : -1e30f;
  float m = val;
#pragma unroll
  for (int o = 1; o < 64; o <<= 1) m = fmaxf(m, __shfl_xor(m, o, 64));
  float e = (lane < KP) ? __expf(val - m) : 0.f;
  float s = e;
#pragma unroll
  for (int o = 1; o < 64; o <<= 1) s += __shfl_xor(s, o, 64);
  return e / s;
}

// v[lane] = sum_k a_k * T[ix_k][64+lane]; split accumulators
__device__ inline float wsum_rows_h(float a, int ix,
                                    const __half* __restrict__ T, int lane) {
  float v0 = 0.f, v1 = 0.f;
#pragma unroll 10
  for (int k = 0; k < KP; k += 2) {
    const int i0 = __builtin_amdgcn_readlane(ix, k);
    const int i1 = __builtin_amdgcn_readlane(ix, k + 1);
    const float a0 = rlanef(a, k);
    const float a1 = rlanef(a, k + 1);
    v0 = fmaf(a0, (float)T[(size_t)i0 * 128 + 64 + lane], v0);
    v1 = fmaf(a1, (float)T[(size_t)i1 * 128 + 64 + lane], v1);
  }
  return v0 + v1;
}

template <bool RELU>
__device__ inline float mv64b(float vin, const float* __restrict__ W,
                              const float* __restrict__ bias, int lane) {
  float acc = bias[lane];
#pragma unroll 8
  for (int j = 0; j < D; ++j)
    acc = fmaf(rlanef(vin, j), W[j * D + lane], acc);
  return RELU ? fmaxf(acc, 0.f) : acc;
}

__device__ inline float mv128b(float lo, float hi, const float* __restrict__ W,
                               const float* __restrict__ bias, int lane) {
  float acc = bias[lane];
#pragma unroll 8
  for (int j = 0; j < D; ++j)
    acc = fmaf(rlanef(lo, j), W[j * D + lane], acc);
#pragma unroll 8
  for (int j = 0; j < D; ++j)
    acc = fmaf(rlanef(hi, j), W[(D + j) * D + lane], acc);
  return fmaxf(acc, 0.f);
}

// ---------------- fused MFMA table kernel ---------------------------------------
// grid = 5 * (NU/16) single-wave blocks.
//  s=0: item gate -> XXA5 rows     s=1: user gate -> FFA5 rows
//  s=2: IAu  s=3: SAu  s=4: UAt   (emb @ W_hi + bias, fp32)
#define LSTR 72  // padded LDS row stride in halves (144B: conflict-free b128)

__global__ __launch_bounds__(64) void k_tabs(
    const float* __restrict__ item_emb, const float* __restrict__ user_emb,
    const float* __restrict__ op_emb, const float* __restrict__ ia_Wg,
    const float* __restrict__ ia_bg, const float* __restrict__ ua_Wg,
    const float* __restrict__ ua_bg, const float* __restrict__ ia_Wa1,
    const float* __restrict__ ia_ba1, const float* __restrict__ sa_Wa1,
    const float* __restrict__ sa_ba1, const float* __restrict__ ua_Wa1,
    const float* __restrict__ ua_ba1, __half* __restrict__ XXA5,
    __half* __restrict__ FFA5, float* __restrict__ IAu,
    float* __restrict__ SAu, float* __restrict__ UAt, int NU_) {
  __shared__ _Float16 ldsX[16 * LSTR];
  __shared__ _Float16 ldsA[16 * LSTR];
  const int lane = threadIdx.x;
  const int nbl = NU_ >> 4;
  const int s = blockIdx.x / nbl, blk = blockIdx.x % nbl;
  const int g0 = blk * 16;
  const int q = lane >> 4, p = lane & 15;

  if (s >= 2) {  // ---- mv jobs: dst = emb @ W_hi + bias ----
    const float* src = (s == 4) ? item_emb : user_emb;
    const float* W = (s == 2)   ? ia_Wa1 + D * D
                     : (s == 3) ? sa_Wa1 + D * D
                                : ua_Wa1 + D * D;
    const float* bias = (s == 2) ? ia_ba1 : (s == 3) ? sa_ba1 : ua_ba1;
    float* dst = (s == 2) ? IAu : (s == 3) ? SAu : UAt;
    half8 a0 = loadA_f32(src + (size_t)g0 * D, 0, lane);
    half8 a1 = loadA_f32(src + (size_t)g0 * D, 1, lane);
#pragma unroll
    for (int t = 0; t < 4; ++t) {
      floatx4 acc = {0.f, 0.f, 0.f, 0.f};
      half8 b0 = loadB_f32(W, 0, t, lane);
      half8 b1 = loadB_f32(W, 1, t, lane);
      acc = __builtin_amdgcn_mfma_f32_16x16x32_f16(a0, b0, acc, 0, 0, 0);
      acc = __builtin_amdgcn_mfma_f32_16x16x32_f16(a1, b1, acc, 0, 0, 0);
      const float bv = bias[16 * t + p];
#pragma unroll
      for (int i = 0; i < 4; ++i)
        dst[(size_t)(g0 + 4 * q + i) * D + 16 * t + p] = acc[i] + bv;
    }
    return;
  }

  // ---- gate jobs ----
  const float* emb = s ? user_emb : item_emb;
  const float* Wg = s ? ua_Wg : ia_Wg;
  const float* bg = s ? ua_bg : ia_bg;
  const float* Wa = s ? ua_Wa1 : ia_Wa1;  // low 64 rows
  __half* dst = s ? FFA5 : XXA5;

  // opbg[r][lane] = bg + op_emb[r] @ Wg_hi   (per-lane d = lane)
  float opbg[5];
#pragma unroll
  for (int r = 0; r < 5; ++r) opbg[r] = bg[lane];
  for (int j = 0; j < D; ++j) {
    const float w = Wg[(size_t)(D + j) * D + lane];
#pragma unroll
    for (int r = 0; r < 5; ++r) opbg[r] = fmaf(op_emb[r * D + j], w, opbg[r]);
  }

  // base = emb16x64 @ Wg_lo  (acc layout: lane holds [4q+i][16t+p])
  half8 a0 = loadA_f32(emb + (size_t)g0 * D, 0, lane);
  half8 a1 = loadA_f32(emb + (size_t)g0 * D, 1, lane);
  floatx4 base[4];
  half8 wa[4][2];
#pragma unroll
  for (int t = 0; t < 4; ++t) {
    base[t] = {0.f, 0.f, 0.f, 0.f};
    half8 b0 = loadB_f32(Wg, 0, t, lane);
    half8 b1 = loadB_f32(Wg, 1, t, lane);
    base[t] = __builtin_amdgcn_mfma_f32_16x16x32_f16(a0, b0, base[t], 0, 0, 0);
    base[t] = __builtin_amdgcn_mfma_f32_16x16x32_f16(a1, b1, base[t], 0, 0, 0);
    wa[t][0] = loadB_f32(Wa, 0, t, lane);
    wa[t][1] = loadB_f32(Wa, 1, t, lane);
  }

  for (int r = 0; r < 5; ++r) {
    // x = relu(base + opbg[r][col]) -> ldsX (f16, padded rows)
#pragma unroll
    for (int t = 0; t < 4; ++t) {
      const float ob = __shfl(opbg[r], p + 16 * t, 64);
#pragma unroll
      for (int i = 0; i < 4; ++i)
        ldsX[(4 * q + i) * LSTR + 16 * t + p] =
            (_Float16)fmaxf(base[t][i] + ob, 0.f);
    }
    // A2-frags straight from LDS (single wave: compiler lgkm waits suffice)
    half8 xa0 = *(const half8*)&ldsX[p * LSTR + 0 * 32 + 8 * q];
    half8 xa1 = *(const half8*)&ldsX[p * LSTR + 1 * 32 + 8 * q];
    floatx4 acc[4];
#pragma unroll
    for (int t = 0; t < 4; ++t) {
      acc[t] = {0.f, 0.f, 0.f, 0.f};
      acc[t] =
          __builtin_amdgcn_mfma_f32_16x16x32_f16(xa0, wa[t][0], acc[t], 0, 0, 0);
      acc[t] =
          __builtin_amdgcn_mfma_f32_16x16x32_f16(xa1, wa[t][1], acc[t], 0, 0, 0);
    }
#pragma unroll
    for (int t = 0; t < 4; ++t)
#pragma unroll
      for (int i = 0; i < 4; ++i)
        ldsA[(4 * q + i) * LSTR + 16 * t + p] = (_Float16)acc[t][i];
    // coalesced 256B row stores: dwords 0..31 = XA half, 32..63 = X half
    const uint32_t* srcbuf =
        (lane < 32) ? (const uint32_t*)ldsA : (const uint32_t*)ldsX;
    const int dl = lane & 31;
    for (int m = 0; m < 16; ++m) {
      const uint32_t val = srcbuf[m * (LSTR / 2) + dl];
      uint32_t* rowp = (uint32_t*)(dst + ((size_t)(g0 + m) * 5 + r) * 128);
      rowp[lane] = val;
    }
  }
}

// ---------------- h_I_all: one wave per user, zero barriers ---------------------
__global__ __launch_bounds__(256, 8) void k_hIall(
    const int* __restrict__ C, const int* __restrict__ Rm,
    const __half* __restrict__ XXA5, const float* __restrict__ IAu,
    const float* __restrict__ ia_Wa2, const float* __restrict__ ia_W,
    const float* __restrict__ ia_b, const float* __restrict__ sa_Wa1,
    __half* __restrict__ HHA) {
  const int lane = threadIdx.x & 63;
  const int u = RFL(blockIdx.x * 4 + (threadIdx.x >> 6));
  const int kk = lane < KP ? lane : KP - 1;
  const int c = C[u * KP + kk];
  const int ix = c * 5 + Rm[(size_t)u * NIT + c];  // random HBM gather
  float sc = score_row_h(XXA5 + (size_t)ix * 128, IAu + (size_t)u * D, ia_Wa2);
  float a = softmax50(sc, lane);
  float v = wsum_rows_h(a, ix, XXA5, lane);
  float h = mv64b<true>(v, ia_W, ia_b, lane);
  float ha = 0.f;
#pragma unroll 8
  for (int j = 0; j < D; ++j)
    ha = fmaf(rlanef(h, j), sa_Wa1[j * D + lane], ha);
  HHA[(size_t)u * 128 + lane] = __float2half(ha);      // HA half (score)
  HHA[(size_t)u * 128 + 64 + lane] = __float2half(h);  // hI half (wsum/MLP)
}

// ---------------- batch: one wave per row, zero barriers ------------------------
__global__ __launch_bounds__(256, 8) void k_batch(
    const int* __restrict__ user_idx, const int* __restrict__ item_idx,
    const int* __restrict__ Nn, const int* __restrict__ Bm,
    const int* __restrict__ Rm, const __half* __restrict__ HHA,
    const __half* __restrict__ FFA5, const float* __restrict__ SAu,
    const float* __restrict__ UAt, const float* __restrict__ sa_Wa2,
    const float* __restrict__ sa_W, const float* __restrict__ sa_b,
    const float* __restrict__ ua_Wa2, const float* __restrict__ ua_W,
    const float* __restrict__ ua_b, const float* __restrict__ fu_W1,
    const float* __restrict__ fu_b1, const float* __restrict__ fu_W2,
    const float* __restrict__ fu_b2, const float* __restrict__ fu_W3,
    const float* __restrict__ fu_b3, const float* __restrict__ rp_W1,
    const float* __restrict__ rp_b1, const float* __restrict__ rp_W2,
    const float* __restrict__ rp_b2, const float* __restrict__ rp_W3,
    const float* __restrict__ rp_b3, float* __restrict__ out) {
  const int lane = threadIdx.x & 63;
  const int b = RFL(blockIdx.x * 4 + (threadIdx.x >> 6));
  const int u = RFL(user_idx[b]);
  const int it = RFL(item_idx[b]);
  const int kk = lane < KP ? lane : KP - 1;
  const int nix = Nn[u * KP + kk];
  const int bn = Bm[it * KP + kk];
  const int ix2 = bn * 5 + Rm[(size_t)bn * NIT + it];
  const float hIu = (float)HHA[(size_t)u * 128 + 64 + lane];
  // ---- phase S ----
  float sc = score_row_h(HHA + (size_t)nix * 128, SAu + (size_t)u * D, sa_Wa2);
  float a = softmax50(sc, lane);
  float v = wsum_rows_h(a, nix, HHA, lane);
  float hS = mv64b<true>(v, sa_W, sa_b, lane);
  // ---- phase Z ----
  float sc2 =
      score_row_h(FFA5 + (size_t)ix2 * 128, UAt + (size_t)it * D, ua_Wa2);
  float a2 = softmax50(sc2, lane);
  float v2 = wsum_rows_h(a2, ix2, FFA5, lane);
  float z = mv64b<true>(v2, ua_W, ua_b, lane);
  // ---- fu MLP ----
  float h = mv128b(hIu, hS, fu_W1, fu_b1, lane);
  h = mv64b<true>(h, fu_W2, fu_b2, lane);
  h = mv64b<true>(h, fu_W3, fu_b3, lane);
  // ---- rp MLP ----
  float g = mv128b(h, z, rp_W1, rp_b1, lane);
  g = mv64b<true>(g, rp_W2, rp_b2, lane);
  float pp = g * rp_W3[lane];
#pragma unroll
  for (int o = 1; o < 64; o <<= 1) pp += __shfl_xor(pp, o, 64);
  if (lane == 0) out[b] = pp + rp_b3[0];
}

extern "C" void kernel_launch(void* const* d_in, const int* in_sizes, int n_in,
                              void* d_out, int out_size, void* d_ws,
                              size_t ws_size, hipStream_t stream) {
  const int* user_idx = (const int*)d_in[0];
  const int* item_idx = (const int*)d_in[1];
  const int* C = (const int*)d_in[2];
  const int* Nn = (const int*)d_in[3];
  const int* Bm = (const int*)d_in[4];
  const int* Rm = (const int*)d_in[5];
  const float* user_emb = (const float*)d_in[6];
  const float* item_emb = (const float*)d_in[7];
  const float* opinion_emb = (const float*)d_in[8];
  const float* ia_Wg = (const float*)d_in[9];
  const float* ia_bg = (const float*)d_in[10];
  const float* ua_Wg = (const float*)d_in[11];
  const float* ua_bg = (const float*)d_in[12];
  const float* ia_Wa1 = (const float*)d_in[13];
  const float* ia_ba1 = (const float*)d_in[14];
  const float* ia_Wa2 = (const float*)d_in[15];
  const float* ia_W = (const float*)d_in[17];
  const float* ia_b = (const float*)d_in[18];
  const float* sa_Wa1 = (const float*)d_in[19];
  const float* sa_ba1 = (const float*)d_in[20];
  const float* sa_Wa2 = (const float*)d_in[21];
  const float* sa_W = (const float*)d_in[23];
  const float* sa_b = (const float*)d_in[24];
  const float* ua_Wa1 = (const float*)d_in[25];
  const float* ua_ba1 = (const float*)d_in[26];
  const float* ua_Wa2 = (const float*)d_in[27];
  const float* ua_W = (const float*)d_in[29];
  const float* ua_b = (const float*)d_in[30];
  const float* fu_W1 = (const float*)d_in[31];
  const float* fu_b1 = (const float*)d_in[32];
  const float* fu_W2 = (const float*)d_in[33];
  const float* fu_b2 = (const float*)d_in[34];
  const float* rp_W1 = (const float*)d_in[35];
  const float* rp_b1 = (const float*)d_in[36];
  const float* rp_W2 = (const float*)d_in[37];
  const float* rp_b2 = (const float*)d_in[38];
  const float* fu_W3 = (const float*)d_in[39];
  const float* fu_b3 = (const float*)d_in[40];
  const float* rp_W3 = (const float*)d_in[41];
  const float* rp_b3 = (const float*)d_in[42];

  const int NU = in_sizes[6] / D;  // 10000 users
  const int B = in_sizes[0];       // 2048

  __half* XXA5 = (__half*)d_ws;                   // NU*5*128 halves
  __half* FFA5 = XXA5 + (size_t)NU * 5 * 128;     // NU*5*128 halves
  __half* HHA = FFA5 + (size_t)NU * 5 * 128;      // NU*128 halves
  float* IAu = (float*)(HHA + (size_t)NU * 128);  // NU*D fp32
  float* SAu = IAu + (size_t)NU * D;
  float* UAt = SAu + (size_t)NU * D;

  const int nbl = NU / 16;  // 625

  k_tabs<<<5 * nbl, 64, 0, stream>>>(item_emb, user_emb, opinion_emb, ia_Wg,
                                     ia_bg, ua_Wg, ua_bg, ia_Wa1, ia_ba1,
                                     sa_Wa1, sa_ba1, ua_Wa1, ua_ba1, XXA5,
                                     FFA5, IAu, SAu, UAt, NU);
  k_hIall<<<NU / 4, 256, 0, stream>>>(C, Rm, XXA5, IAu, ia_Wa2, ia_W, ia_b,
                                      sa_Wa1, HHA);
  k_batch<<<B / 4, 256, 0, stream>>>(user_idx, item_idx, Nn, Bm, Rm, HHA, FFA5,
                                     SAu, UAt, sa_Wa2, sa_W, sa_b, ua_Wa2,
                                     ua_W, ua_b, fu_W1, fu_b1, fu_W2, fu_b2,
                                     fu_W3, fu_b3, rp_W1, rp_b1, rp_W2, rp_b2,
                                     rp_W3, rp_b3, (float*)d_out);
}